// Round 1
// baseline (173.015 us; speedup 1.0000x reference)
//
#include <hip/hip_runtime.h>

// Problem constants
#define HW 4096           // H*W
#define CHW 262144        // C*H*W
#define OUT_ELEMS 4194304 // B*C*H*W
#define FLT_BIG 3.4e38f

typedef __attribute__((ext_vector_type(8))) short  short8;   // MFMA A/B frag (4 VGPR)
typedef __attribute__((ext_vector_type(4))) float  floatx4;  // MFMA C/D frag
typedef __attribute__((ext_vector_type(4))) int    intx4;

// ws layout:
//   [0,2048)        enorm f32[512]   -- holds -0.5*||e||^2 (R12: prescaled)
//   [4096,135168)   planes_frag u16 (128 KB, fragment-major split-bf16 codebook)
//   [135168,135424) ssep double[32]  (SSE partials, f64 atomicAdd)
//   [135424,137472) hist u32[512]    (global histogram, atomicAdd)
//   [137472,137476) done u32         (block completion counter)
// hist/done/ssep are zeroed by vq_prep each launch (graph-replay safe).

__device__ __forceinline__ unsigned bf16_rne(float f) {
    unsigned u = __float_as_uint(f);
    return (u + 0x7FFFu + ((u >> 16) & 1u)) >> 16;  // RNE bf16 bits
}

__device__ __forceinline__ void split8(const float* f, intx4* hi, intx4* lo) {
    unsigned h[4], l[4];
#pragma unroll
    for (int j = 0; j < 4; ++j) {
        const unsigned h0 = bf16_rne(f[2 * j]);
        const unsigned h1 = bf16_rne(f[2 * j + 1]);
        const float hf0 = __uint_as_float(h0 << 16);
        const float hf1 = __uint_as_float(h1 << 16);
        const unsigned l0 = bf16_rne(f[2 * j] - hf0);
        const unsigned l1 = bf16_rne(f[2 * j + 1] - hf1);
        h[j] = h0 | (h1 << 16);
        l[j] = l0 | (l1 << 16);
    }
    *hi = intx4{(int)h[0], (int)h[1], (int)h[2], (int)h[3]};
    *lo = intx4{(int)l[0], (int)l[1], (int)l[2], (int)l[3]};
}

// prep: 128 blocks x 256 threads; 4 codes/block (1 wave per code), single
// iteration (R12: was 16 blocks x 8 serial iters). Also zeroes the fused-tail
// state (hist/done/ssep). enorm is stored PRESCALED as -0.5*||e||^2 so the
// main kernel can load it directly as the MFMA accumulator init.
__global__ void vq_prep(const float* __restrict__ emb,
                        unsigned short* __restrict__ pfrag,
                        float* __restrict__ enorm,
                        unsigned* __restrict__ hist,
                        unsigned* __restrict__ done,
                        double* __restrict__ ssep) {
    const int t = threadIdx.x;
    const int lane = t & 63;
    if (blockIdx.x == 0) {
        hist[t] = 0u; hist[t + 256] = 0u;
        if (t == 0) *done = 0u;
        if (t < 32) ssep[t] = 0.0;
    }
    const int code = (blockIdx.x << 2) + (t >> 6);
    const int c = lane;
    const float v = emb[(code << 6) + c];            // 256B coalesced per wave
    const unsigned hb = bf16_rne(v);
    const float hf    = __uint_as_float(hb << 16);
    const unsigned lb = bf16_rne(v - hf);
    const int nc = code >> 6, grp = (code & 63) >> 4, n = code & 15;
    const int q = (c & 31) >> 3, o = c & 7;
    const int jh = c >> 5;        // eh element e=c
    const int jl = 2 + (c >> 5);  // el element e=64+c
    pfrag[((((size_t)(nc*4 + jh)*4 + grp)*4 + q)*16 + n)*8 + o] = (unsigned short)hb;
    pfrag[((((size_t)(nc*4 + jl)*4 + grp)*4 + q)*16 + n)*8 + o] = (unsigned short)lb;
    float s = v * v;
#pragma unroll
    for (int off = 32; off > 0; off >>= 1) s += __shfl_xor(s, off, 64);
    if (lane == 0) enorm[code] = -0.5f * s;
}

// Main: 2048 blocks x 256 threads; 32 rows/block.
// R12 changes vs R11:
//  * MFMA operands swapped (codes frag = A, x frag = B): each lane now owns
//    one x-row (col=lane&15) with 16 codes in (quad,reg). A/B fragments share
//    the same lane layout, so the swap is pure argument order.
//  * enorm folded into the accumulator init (acc starts at -0.5*||e||^2, so
//    acc_final = dot - ||e||^2/2 = -d/2). The per-distance fmaf disappears;
//    selection tracks MAX acc with lowest-index tie-break (iteration order is
//    code-ascending per track, so strict ">" preserves first-occurrence).
//  * Cross-lane tournament: 2 shfl rounds over quads (off 16,32) on a single
//    merged track, vs 4 rounds x 4 tracks in R11.
//  * hist fused in (global atomicAdd per row), SSE via f64 atomicAdd into 32
//    partials, and a done-counter last-block tail computes the scalars
//    (agent-scope atomics + threadfence: cross-XCD safe).
// Exact fp64 verify of top-2 candidates is unchanged.
__global__ __launch_bounds__(256)
void vq_main(const float* __restrict__ x_in, const float* __restrict__ emb,
             const unsigned short* __restrict__ pfrag,
             const float* __restrict__ enorm,
             const float* __restrict__ weight,
             float* __restrict__ out, float* __restrict__ idx_out,
             float* __restrict__ scal,
             unsigned* __restrict__ hist, unsigned* __restrict__ done,
             double* __restrict__ ssep) {
    __shared__ float  b1s[2][32], b2s[2][32];
    __shared__ int    i1s[2][32], i2s[2][32];
    __shared__ int    c1i[32], c2i[32], qidx[32];
    __shared__ double parts[8][32];
    __shared__ double ls_red[4];
    __shared__ int    lastf;

    const int t     = threadIdx.x;
    const int lane  = t & 63;
    const int wv    = t >> 6;
    const int col   = lane & 15;
    const int quad  = lane >> 4;
    const int blk   = blockIdx.x;
    const int mrow0 = (wv >> 1) << 4;   // wave row base (0/16)
    const int khalf = wv & 1;           // code-half of each 64-chunk
    const int ncol0 = khalf << 5;
    const int half = blk & 1;           // which 32-w half of the stripe
    const int bh = blk >> 1;
    const int b = bh >> 6, h = bh & 63;
    const float* xb = x_in + (size_t)b * CHW + h * 64 + (half << 5);

    // ---- X-frags: one 16-row M-tile, direct from BCHW global (coalesced),
    // split-bf16, register-resident. Used as the MFMA *B* operand (R12). ----
    short8 Xh[2], Xl[2];
#pragma unroll
    for (int u = 0; u < 2; ++u) {
        float f[8];
#pragma unroll
        for (int j = 0; j < 8; ++j) {
            const int c = (u << 5) + (quad << 3) + j;
            f[j] = xb[(size_t)c * HW + mrow0 + col];
        }
        intx4 hi, lo;
        split8(f, &hi, &lo);
        Xh[u] = __builtin_bit_cast(short8, hi);
        Xl[u] = __builtin_bit_cast(short8, lo);
    }

    // Two per-lane top-2 tracks (nt=0 / nt=1) for ILP; merged before butterfly.
    float B1a = -FLT_BIG, B2a = -FLT_BIG, B1b = -FLT_BIG, B2b = -FLT_BIG;
    int   I1a = 0x3FFFFFFF, I2a = 0x3FFFFFFF, I1b = 0x3FFFFFFF, I2b = 0x3FFFFFFF;

    const char*  pf  = (const char*)pfrag + (size_t)lane * 16 + ((size_t)khalf << 11);
    const float* enp = enorm + ncol0 + (quad << 2);

#pragma unroll 2
    for (int nc = 0; nc < 8; ++nc) {
        const char* base = pf + ((size_t)nc << 14);
        const int K0 = nc << 6;
        // acc init = -0.5*||e||^2 for this lane's 4 codes (contiguous float4)
        floatx4 a0 = *(const floatx4*)(enp + K0);
        floatx4 a1 = *(const floatx4*)(enp + K0 + 16);
#define BLD(j, g) (*(const short8*)(base + ((j) << 12) + ((g) << 10)))
        {   // j=0: eh c[0,32) x {xh,xl}
            const short8 e0 = BLD(0, 0), e1 = BLD(0, 1);
            a0 = __builtin_amdgcn_mfma_f32_16x16x32_bf16(e0, Xh[0], a0, 0, 0, 0);
            a1 = __builtin_amdgcn_mfma_f32_16x16x32_bf16(e1, Xh[0], a1, 0, 0, 0);
            a0 = __builtin_amdgcn_mfma_f32_16x16x32_bf16(e0, Xl[0], a0, 0, 0, 0);
            a1 = __builtin_amdgcn_mfma_f32_16x16x32_bf16(e1, Xl[0], a1, 0, 0, 0);
        }
        {   // j=1: eh c[32,64) x {xh,xl}
            const short8 e0 = BLD(1, 0), e1 = BLD(1, 1);
            a0 = __builtin_amdgcn_mfma_f32_16x16x32_bf16(e0, Xh[1], a0, 0, 0, 0);
            a1 = __builtin_amdgcn_mfma_f32_16x16x32_bf16(e1, Xh[1], a1, 0, 0, 0);
            a0 = __builtin_amdgcn_mfma_f32_16x16x32_bf16(e0, Xl[1], a0, 0, 0, 0);
            a1 = __builtin_amdgcn_mfma_f32_16x16x32_bf16(e1, Xl[1], a1, 0, 0, 0);
        }
        {   // j=2: el c[0,32) x xh
            const short8 e0 = BLD(2, 0), e1 = BLD(2, 1);
            a0 = __builtin_amdgcn_mfma_f32_16x16x32_bf16(e0, Xh[0], a0, 0, 0, 0);
            a1 = __builtin_amdgcn_mfma_f32_16x16x32_bf16(e1, Xh[0], a1, 0, 0, 0);
        }
        {   // j=3: el c[32,64) x xh
            const short8 e0 = BLD(3, 0), e1 = BLD(3, 1);
            a0 = __builtin_amdgcn_mfma_f32_16x16x32_bf16(e0, Xh[1], a0, 0, 0, 0);
            a1 = __builtin_amdgcn_mfma_f32_16x16x32_bf16(e1, Xh[1], a1, 0, 0, 0);
        }
#undef BLD

        const int cb = K0 + ncol0 + (quad << 2);
#pragma unroll
        for (int reg = 0; reg < 4; ++reg) {
            const float da = a0[reg];   // acc = -d/2: larger = closer
            if (da > B1a)      { B2a = B1a; I2a = I1a; B1a = da; I1a = cb + reg; }
            else if (da > B2a) { B2a = da; I2a = cb + reg; }
            const float db = a1[reg];
            if (db > B1b)      { B2b = B1b; I2b = I1b; B1b = db; I1b = cb + 16 + reg; }
            else if (db > B2b) { B2b = db; I2b = cb + 16 + reg; }
        }
    }

    // ---- merge the two tracks (disjoint code sets, index tie-break) ----
    float B1, B2; int I1, I2;
    if (B1b > B1a || (B1b == B1a && I1b < I1a)) {
        B1 = B1b; I1 = I1b;
        if (B1a > B2b || (B1a == B2b && I1a < I2b)) { B2 = B1a; I2 = I1a; }
        else                                        { B2 = B2b; I2 = I2b; }
    } else {
        B1 = B1a; I1 = I1a;
        if (B1b > B2a || (B1b == B2a && I1b < I2a)) { B2 = B1b; I2 = I1b; }
        else                                        { B2 = B2a; I2 = I2a; }
    }

    // ---- cross-lane top-2 butterfly over QUADS only (off 16,32): each lane
    // already owns a full row slice; disjoint code sets, explicit tie-break ----
#pragma unroll
    for (int off = 16; off <= 32; off <<= 1) {
        const float ob1 = __shfl_xor(B1, off, 64);
        const int   oi1 = __shfl_xor(I1, off, 64);
        const float ob2 = __shfl_xor(B2, off, 64);
        const int   oi2 = __shfl_xor(I2, off, 64);
        if (ob1 > B1 || (ob1 == B1 && oi1 < I1)) {
            float nb2; int ni2;
            if (B1 > ob2 || (B1 == ob2 && I1 < oi2)) { nb2 = B1; ni2 = I1; }
            else                                     { nb2 = ob2; ni2 = oi2; }
            B1 = ob1; I1 = oi1; B2 = nb2; I2 = ni2;
        } else if (ob1 > B2 || (ob1 == B2 && oi1 < I2)) {
            B2 = ob1; I2 = oi1;
        }
    }
    if (lane < 16) {
        const int row = mrow0 + lane;
        b1s[khalf][row] = B1; b2s[khalf][row] = B2;
        i1s[khalf][row] = I1; i2s[khalf][row] = I2;
    }
    __syncthreads();

    // ---- merge halves -> approx top-2 candidates per row (max-flipped) ----
    if (t < 32) {
        const int r = t;
        float b1 = b1s[0][r], b2 = b2s[0][r];
        int   i1 = i1s[0][r], i2 = i2s[0][r];
        const float c1 = b1s[1][r]; const int j1 = i1s[1][r];
        const float c2 = b2s[1][r]; const int j2 = i2s[1][r];
        if (c1 > b1 || (c1 == b1 && j1 < i1))      { b2 = b1; i2 = i1; b1 = c1; i1 = j1; }
        else if (c1 > b2 || (c1 == b2 && j1 < i2)) { b2 = c1; i2 = j1; }
        if (c2 > b2 || (c2 == b2 && j2 < i2))      { b2 = c2; i2 = j2; }
        c1i[r] = i1; c2i[r] = i2;
    }
    __syncthreads();

    // ---- unconditional 8-way-parallel exact fp64 verify of both candidates:
    // thread group k = t>>5 -> candidate (k&1), c-quarter (k>>1), 16 c each ----
    {
        const int r  = t & 31;
        const int k  = t >> 5;
        const int cq = k >> 1;
        const int code = (k & 1) ? c2i[r] : c1i[r];
        const float* ep = emb + ((size_t)code << 6) + (cq << 4);
        const float* xq = xb + r;   // lanes r consecutive -> coalesced
        double d0 = 0.0, d1 = 0.0;
#pragma unroll
        for (int cc = 0; cc < 16; cc += 2) {
            const int c = (cq << 4) + cc;
            const double f0 = (double)xq[(size_t)c * HW]       - (double)ep[cc];
            const double f1 = (double)xq[(size_t)(c + 1) * HW] - (double)ep[cc + 1];
            d0 = fma(f0, f0, d0);
            d1 = fma(f1, f1, d1);
        }
        parts[k][r] = d0 + d1;
    }
    __syncthreads();
    if (t < 32) {
        const double d1 = parts[0][t] + parts[2][t] + parts[4][t] + parts[6][t];
        const double d2 = parts[1][t] + parts[3][t] + parts[5][t] + parts[7][t];
        int i1 = c1i[t];
        const int i2 = c2i[t];
        if (d2 < d1 || (d2 == d1 && i2 < i1)) i1 = i2; // lowest-index tie-break
        qidx[t] = i1;
        idx_out[(blk << 5) + t] = (float)i1;
        atomicAdd(&hist[i1], 1u);                      // fused histogram
    }
    __syncthreads();

    // ---- epilogue: quantized out (coalesced along w) + per-block SSE ----
    {
        const int r  = t & 31;
        const int c0 = (t >> 5) << 3;    // 8 channels per thread-group
        const float* xp = xb + r;
        float*       op = out + (size_t)b * CHW + h * 64 + (half << 5) + r;
        const float* eq = emb + ((size_t)qidx[r] << 6);
        float sse_local = 0.f;
#pragma unroll
        for (int cc = 0; cc < 8; ++cc) {
            const int c = c0 + cc;
            const float qc = eq[c];
            const float dx = qc - xp[(size_t)c * HW];
            sse_local = fmaf(dx, dx, sse_local);
            op[(size_t)c * HW] = qc;
        }
#pragma unroll
        for (int off = 32; off > 0; off >>= 1)
            sse_local += __shfl_down(sse_local, off, 64);
        if (lane == 0) ls_red[wv] = (double)sse_local;
        __syncthreads();
        if (t == 0)
            atomicAdd(&ssep[blk & 31],
                      (ls_red[0] + ls_red[1]) + (ls_red[2] + ls_red[3]));
    }

    // ---- fused tail: last finished block computes the three scalars.
    // hist/ssep are agent-scope atomics (performed at the coherent point);
    // the syncthreads above drained them, threadfence orders vs done-add. ----
    if (t == 0) {
        __threadfence();
        lastf = (atomicAdd(done, 1u) == 2047u) ? 1 : 0;
    }
    __syncthreads();
    if (lastf) {
        __threadfence();   // acquire side
        double term = 0.0; int act = 0;
#pragma unroll
        for (int j = 0; j < 2; ++j) {
            const int k = t + (j << 8);
            const unsigned cnt =
                __hip_atomic_load(&hist[k], __ATOMIC_RELAXED, __HIP_MEMORY_SCOPE_AGENT);
            const double pr = (double)cnt * (1.0 / 65536.0);
            term += pr * log(pr + 1e-10);
            act  += (weight[k] >= 0.01f) ? 1 : 0;
        }
#pragma unroll
        for (int off = 32; off > 0; off >>= 1) {
            term += __shfl_down(term, off, 64);
            act  += __shfl_down(act,  off, 64);
        }
        if (lane == 0) { ls_red[wv] = term; c1i[wv] = act; }
        __syncthreads();
        if (t == 0) {
            const double s = (ls_red[0] + ls_red[1]) + (ls_red[2] + ls_red[3]);
            const int    a = c1i[0] + c1i[1] + c1i[2] + c1i[3];
            double ss = 0.0;
#pragma unroll
            for (int p = 0; p < 32; ++p)
                ss += __hip_atomic_load(&ssep[p], __ATOMIC_RELAXED, __HIP_MEMORY_SCOPE_AGENT);
            scal[0] = (float)(ss * (1.0 / 4194304.0));  // commitment_loss
            scal[1] = (float)exp(-s);                   // perplexity
            scal[2] = (float)a;                         // active_codes
        }
    }
}

extern "C" void kernel_launch(void* const* d_in, const int* in_sizes, int n_in,
                              void* d_out, int out_size, void* d_ws, size_t ws_size,
                              hipStream_t stream) {
    const float* x      = (const float*)d_in[0];  // [16,64,64,64] fp32
    const float* emb    = (const float*)d_in[1];  // [512,64] fp32
    const float* weight = (const float*)d_in[2];  // [512] fp32

    float* out = (float*)d_out;
    float*          enorm = (float*)d_ws;
    unsigned short* pfrag = (unsigned short*)((char*)d_ws + 4096);
    double*         ssep  = (double*)((char*)d_ws + 135168);
    unsigned*       hist  = (unsigned*)((char*)d_ws + 135424);
    unsigned*       done  = (unsigned*)((char*)d_ws + 137472);

    float* scal    = out + OUT_ELEMS;      // commitment, perplexity, active
    float* idx_out = out + OUT_ELEMS + 3;  // indices as float [65536]

    vq_prep<<<128, 256, 0, stream>>>(emb, pfrag, enorm, hist, done, ssep);
    vq_main<<<2048, 256, 0, stream>>>(x, emb, pfrag, enorm, weight,
                                      out, idx_out, scal, hist, done, ssep);
}

// Round 2
// 139.811 us; speedup vs baseline: 1.2375x; 1.2375x over previous
//
#include <hip/hip_runtime.h>

// Problem constants
#define HW 4096           // H*W
#define CHW 262144        // C*H*W
#define OUT_ELEMS 4194304 // B*C*H*W
#define FLT_BIG 3.4e38f

typedef __attribute__((ext_vector_type(8))) short  short8;   // MFMA A/B frag (4 VGPR)
typedef __attribute__((ext_vector_type(4))) float  floatx4;  // MFMA C/D frag
typedef __attribute__((ext_vector_type(4))) int    intx4;

// ws layout:
//   [0,2048)        enorm f32[512]   -- holds -0.5*||e||^2 (prescaled)
//   [4096,135168)   planes_frag u16 (128 KB, fragment-major split-bf16 codebook)
//   [135168,135424) ssep double[32]  (SSE partials, f64 atomicAdd)
//   [135424,137472) hist u32[512]    (global histogram, atomicAdd)
//   [137472,137476) done u32         (block completion counter)
// hist/done/ssep are zeroed by vq_prep each launch (graph-replay safe).

__device__ __forceinline__ unsigned bf16_rne(float f) {
    unsigned u = __float_as_uint(f);
    return (u + 0x7FFFu + ((u >> 16) & 1u)) >> 16;  // RNE bf16 bits
}

__device__ __forceinline__ void split8(const float* f, intx4* hi, intx4* lo) {
    unsigned h[4], l[4];
#pragma unroll
    for (int j = 0; j < 4; ++j) {
        const unsigned h0 = bf16_rne(f[2 * j]);
        const unsigned h1 = bf16_rne(f[2 * j + 1]);
        const float hf0 = __uint_as_float(h0 << 16);
        const float hf1 = __uint_as_float(h1 << 16);
        const unsigned l0 = bf16_rne(f[2 * j] - hf0);
        const unsigned l1 = bf16_rne(f[2 * j + 1] - hf1);
        h[j] = h0 | (h1 << 16);
        l[j] = l0 | (l1 << 16);
    }
    *hi = intx4{(int)h[0], (int)h[1], (int)h[2], (int)h[3]};
    *lo = intx4{(int)l[0], (int)l[1], (int)l[2], (int)l[3]};
}

// prep: 128 blocks x 256 threads; 4 codes/block (1 wave per code). Also zeroes
// the fused-tail state (hist/done/ssep). enorm stored PRESCALED (-0.5*||e||^2).
__global__ void vq_prep(const float* __restrict__ emb,
                        unsigned short* __restrict__ pfrag,
                        float* __restrict__ enorm,
                        unsigned* __restrict__ hist,
                        unsigned* __restrict__ done,
                        double* __restrict__ ssep) {
    const int t = threadIdx.x;
    const int lane = t & 63;
    if (blockIdx.x == 0) {
        hist[t] = 0u; hist[t + 256] = 0u;
        if (t == 0) *done = 0u;
        if (t < 32) ssep[t] = 0.0;
    }
    const int code = (blockIdx.x << 2) + (t >> 6);
    const int c = lane;
    const float v = emb[(code << 6) + c];            // 256B coalesced per wave
    const unsigned hb = bf16_rne(v);
    const float hf    = __uint_as_float(hb << 16);
    const unsigned lb = bf16_rne(v - hf);
    const int nc = code >> 6, grp = (code & 63) >> 4, n = code & 15;
    const int q = (c & 31) >> 3, o = c & 7;
    const int jh = c >> 5;        // eh element e=c
    const int jl = 2 + (c >> 5);  // el element e=64+c
    pfrag[((((size_t)(nc*4 + jh)*4 + grp)*4 + q)*16 + n)*8 + o] = (unsigned short)hb;
    pfrag[((((size_t)(nc*4 + jl)*4 + grp)*4 + q)*16 + n)*8 + o] = (unsigned short)lb;
    float s = v * v;
#pragma unroll
    for (int off = 32; off > 0; off >>= 1) s += __shfl_xor(s, off, 64);
    if (lane == 0) enorm[code] = -0.5f * s;
}

// Main: 2048 blocks x 256 threads; 32 rows/block.
// R13 changes vs R12 (which regressed 61->113us):
//  * NO __threadfence(). R12's per-block agent fence lowered to buffer_wbl2
//    (whole-L2 writeback walk) x 2048 blocks -> memory pipe saturated, VALU
//    busy collapsed 55%->16%. The tail only reads hist/ssep, which are written
//    via device-scope atomic RMWs (performed at the coherent point) -- no L2
//    writeback is needed to publish them. Ordering "my atomics done before I
//    bump done" is exactly s_waitcnt vmcnt(0) (hist atomics already drained by
//    the preceding __syncthreads; only t0's ssep add is in flight).
//  * enorm off the MFMA critical path: accs zero-init again, the -0.5*||e||^2
//    float4s load at iteration top (no consumer until selection) and are
//    added at selection time. Monotone + same tie-break order; exact fp64
//    verify of top-2 unchanged.
// Carried from R12: swapped MFMA operands (codes=A, x=B; selection fmaf gone,
// butterfly 2 rounds x 1 track), fused hist atomics, done-counter tail.
__global__ __launch_bounds__(256)
void vq_main(const float* __restrict__ x_in, const float* __restrict__ emb,
             const unsigned short* __restrict__ pfrag,
             const float* __restrict__ enorm,
             const float* __restrict__ weight,
             float* __restrict__ out, float* __restrict__ idx_out,
             float* __restrict__ scal,
             unsigned* __restrict__ hist, unsigned* __restrict__ done,
             double* __restrict__ ssep) {
    __shared__ float  b1s[2][32], b2s[2][32];
    __shared__ int    i1s[2][32], i2s[2][32];
    __shared__ int    c1i[32], c2i[32], qidx[32];
    __shared__ double parts[8][32];
    __shared__ double ls_red[4];
    __shared__ int    lastf;

    const int t     = threadIdx.x;
    const int lane  = t & 63;
    const int wv    = t >> 6;
    const int col   = lane & 15;
    const int quad  = lane >> 4;
    const int blk   = blockIdx.x;
    const int mrow0 = (wv >> 1) << 4;   // wave row base (0/16)
    const int khalf = wv & 1;           // code-half of each 64-chunk
    const int ncol0 = khalf << 5;
    const int half = blk & 1;           // which 32-w half of the stripe
    const int bh = blk >> 1;
    const int b = bh >> 6, h = bh & 63;
    const float* xb = x_in + (size_t)b * CHW + h * 64 + (half << 5);

    // ---- X-frags: one 16-row M-tile, direct from BCHW global (coalesced),
    // split-bf16, register-resident. Used as the MFMA *B* operand. ----
    short8 Xh[2], Xl[2];
#pragma unroll
    for (int u = 0; u < 2; ++u) {
        float f[8];
#pragma unroll
        for (int j = 0; j < 8; ++j) {
            const int c = (u << 5) + (quad << 3) + j;
            f[j] = xb[(size_t)c * HW + mrow0 + col];
        }
        intx4 hi, lo;
        split8(f, &hi, &lo);
        Xh[u] = __builtin_bit_cast(short8, hi);
        Xl[u] = __builtin_bit_cast(short8, lo);
    }

    // Two per-lane top-2 tracks (nt=0 / nt=1) for ILP; merged before butterfly.
    float B1a = -FLT_BIG, B2a = -FLT_BIG, B1b = -FLT_BIG, B2b = -FLT_BIG;
    int   I1a = 0x3FFFFFFF, I2a = 0x3FFFFFFF, I1b = 0x3FFFFFFF, I2b = 0x3FFFFFFF;

    const char*  pf  = (const char*)pfrag + (size_t)lane * 16 + ((size_t)khalf << 11);
    const float* enp = enorm + ncol0 + (quad << 2);

#pragma unroll 2
    for (int nc = 0; nc < 8; ++nc) {
        const char* base = pf + ((size_t)nc << 14);
        const int K0 = nc << 6;
        // -0.5*||e||^2 for this lane's 8 codes; loads issue here, first use is
        // at selection below -> fully hidden under the MFMA chain.
        const floatx4 e0v = *(const floatx4*)(enp + K0);
        const floatx4 e1v = *(const floatx4*)(enp + K0 + 16);
        floatx4 a0{0.f,0.f,0.f,0.f}, a1{0.f,0.f,0.f,0.f};
#define BLD(j, g) (*(const short8*)(base + ((j) << 12) + ((g) << 10)))
        {   // j=0: eh c[0,32) x {xh,xl}
            const short8 e0 = BLD(0, 0), e1 = BLD(0, 1);
            a0 = __builtin_amdgcn_mfma_f32_16x16x32_bf16(e0, Xh[0], a0, 0, 0, 0);
            a1 = __builtin_amdgcn_mfma_f32_16x16x32_bf16(e1, Xh[0], a1, 0, 0, 0);
            a0 = __builtin_amdgcn_mfma_f32_16x16x32_bf16(e0, Xl[0], a0, 0, 0, 0);
            a1 = __builtin_amdgcn_mfma_f32_16x16x32_bf16(e1, Xl[0], a1, 0, 0, 0);
        }
        {   // j=1: eh c[32,64) x {xh,xl}
            const short8 e0 = BLD(1, 0), e1 = BLD(1, 1);
            a0 = __builtin_amdgcn_mfma_f32_16x16x32_bf16(e0, Xh[1], a0, 0, 0, 0);
            a1 = __builtin_amdgcn_mfma_f32_16x16x32_bf16(e1, Xh[1], a1, 0, 0, 0);
            a0 = __builtin_amdgcn_mfma_f32_16x16x32_bf16(e0, Xl[1], a0, 0, 0, 0);
            a1 = __builtin_amdgcn_mfma_f32_16x16x32_bf16(e1, Xl[1], a1, 0, 0, 0);
        }
        {   // j=2: el c[0,32) x xh
            const short8 e0 = BLD(2, 0), e1 = BLD(2, 1);
            a0 = __builtin_amdgcn_mfma_f32_16x16x32_bf16(e0, Xh[0], a0, 0, 0, 0);
            a1 = __builtin_amdgcn_mfma_f32_16x16x32_bf16(e1, Xh[0], a1, 0, 0, 0);
        }
        {   // j=3: el c[32,64) x xh
            const short8 e0 = BLD(3, 0), e1 = BLD(3, 1);
            a0 = __builtin_amdgcn_mfma_f32_16x16x32_bf16(e0, Xh[1], a0, 0, 0, 0);
            a1 = __builtin_amdgcn_mfma_f32_16x16x32_bf16(e1, Xh[1], a1, 0, 0, 0);
        }
#undef BLD

        const int cb = K0 + ncol0 + (quad << 2);
#pragma unroll
        for (int reg = 0; reg < 4; ++reg) {
            const float da = a0[reg] + e0v[reg];   // = dot - ||e||^2/2 = -d/2
            if (da > B1a)      { B2a = B1a; I2a = I1a; B1a = da; I1a = cb + reg; }
            else if (da > B2a) { B2a = da; I2a = cb + reg; }
            const float db = a1[reg] + e1v[reg];
            if (db > B1b)      { B2b = B1b; I2b = I1b; B1b = db; I1b = cb + 16 + reg; }
            else if (db > B2b) { B2b = db; I2b = cb + 16 + reg; }
        }
    }

    // ---- merge the two tracks (disjoint code sets, index tie-break) ----
    float B1, B2; int I1, I2;
    if (B1b > B1a || (B1b == B1a && I1b < I1a)) {
        B1 = B1b; I1 = I1b;
        if (B1a > B2b || (B1a == B2b && I1a < I2b)) { B2 = B1a; I2 = I1a; }
        else                                        { B2 = B2b; I2 = I2b; }
    } else {
        B1 = B1a; I1 = I1a;
        if (B1b > B2a || (B1b == B2a && I1b < I2a)) { B2 = B1b; I2 = I1b; }
        else                                        { B2 = B2a; I2 = I2a; }
    }

    // ---- cross-lane top-2 butterfly over QUADS only (off 16,32) ----
#pragma unroll
    for (int off = 16; off <= 32; off <<= 1) {
        const float ob1 = __shfl_xor(B1, off, 64);
        const int   oi1 = __shfl_xor(I1, off, 64);
        const float ob2 = __shfl_xor(B2, off, 64);
        const int   oi2 = __shfl_xor(I2, off, 64);
        if (ob1 > B1 || (ob1 == B1 && oi1 < I1)) {
            float nb2; int ni2;
            if (B1 > ob2 || (B1 == ob2 && I1 < oi2)) { nb2 = B1; ni2 = I1; }
            else                                     { nb2 = ob2; ni2 = oi2; }
            B1 = ob1; I1 = oi1; B2 = nb2; I2 = ni2;
        } else if (ob1 > B2 || (ob1 == B2 && oi1 < I2)) {
            B2 = ob1; I2 = oi1;
        }
    }
    if (lane < 16) {
        const int row = mrow0 + lane;
        b1s[khalf][row] = B1; b2s[khalf][row] = B2;
        i1s[khalf][row] = I1; i2s[khalf][row] = I2;
    }
    __syncthreads();

    // ---- merge halves -> approx top-2 candidates per row (max-flipped) ----
    if (t < 32) {
        const int r = t;
        float b1 = b1s[0][r], b2 = b2s[0][r];
        int   i1 = i1s[0][r], i2 = i2s[0][r];
        const float c1 = b1s[1][r]; const int j1 = i1s[1][r];
        const float c2 = b2s[1][r]; const int j2 = i2s[1][r];
        if (c1 > b1 || (c1 == b1 && j1 < i1))      { b2 = b1; i2 = i1; b1 = c1; i1 = j1; }
        else if (c1 > b2 || (c1 == b2 && j1 < i2)) { b2 = c1; i2 = j1; }
        if (c2 > b2 || (c2 == b2 && j2 < i2))      { b2 = c2; i2 = j2; }
        c1i[r] = i1; c2i[r] = i2;
    }
    __syncthreads();

    // ---- unconditional 8-way-parallel exact fp64 verify of both candidates:
    // thread group k = t>>5 -> candidate (k&1), c-quarter (k>>1), 16 c each ----
    {
        const int r  = t & 31;
        const int k  = t >> 5;
        const int cq = k >> 1;
        const int code = (k & 1) ? c2i[r] : c1i[r];
        const float* ep = emb + ((size_t)code << 6) + (cq << 4);
        const float* xq = xb + r;   // lanes r consecutive -> coalesced
        double d0 = 0.0, d1 = 0.0;
#pragma unroll
        for (int cc = 0; cc < 16; cc += 2) {
            const int c = (cq << 4) + cc;
            const double f0 = (double)xq[(size_t)c * HW]       - (double)ep[cc];
            const double f1 = (double)xq[(size_t)(c + 1) * HW] - (double)ep[cc + 1];
            d0 = fma(f0, f0, d0);
            d1 = fma(f1, f1, d1);
        }
        parts[k][r] = d0 + d1;
    }
    __syncthreads();
    if (t < 32) {
        const double d1 = parts[0][t] + parts[2][t] + parts[4][t] + parts[6][t];
        const double d2 = parts[1][t] + parts[3][t] + parts[5][t] + parts[7][t];
        int i1 = c1i[t];
        const int i2 = c2i[t];
        if (d2 < d1 || (d2 == d1 && i2 < i1)) i1 = i2; // lowest-index tie-break
        qidx[t] = i1;
        idx_out[(blk << 5) + t] = (float)i1;
        atomicAdd(&hist[i1], 1u);                      // fused histogram
    }
    __syncthreads();   // also drains every thread's hist atomic (vmcnt 0)

    // ---- epilogue: quantized out (coalesced along w) + per-block SSE ----
    {
        const int r  = t & 31;
        const int c0 = (t >> 5) << 3;    // 8 channels per thread-group
        const float* xp = xb + r;
        float*       op = out + (size_t)b * CHW + h * 64 + (half << 5) + r;
        const float* eq = emb + ((size_t)qidx[r] << 6);
        float sse_local = 0.f;
#pragma unroll
        for (int cc = 0; cc < 8; ++cc) {
            const int c = c0 + cc;
            const float qc = eq[c];
            const float dx = qc - xp[(size_t)c * HW];
            sse_local = fmaf(dx, dx, sse_local);
            op[(size_t)c * HW] = qc;
        }
#pragma unroll
        for (int off = 32; off > 0; off >>= 1)
            sse_local += __shfl_down(sse_local, off, 64);
        if (lane == 0) ls_red[wv] = (double)sse_local;
        __syncthreads();
        if (t == 0)
            atomicAdd(&ssep[blk & 31],
                      (ls_red[0] + ls_red[1]) + (ls_red[2] + ls_red[3]));
    }

    // ---- fused tail: last finished block computes the three scalars.
    // hist/ssep are only ever written via device-scope atomic RMWs (performed
    // at the coherent point) -> no cache-maintenance fence needed. Only
    // ordering needed: t0's in-flight ssep add completes before the done
    // bump -> s_waitcnt vmcnt(0). (hist atomics were drained by the
    // __syncthreads above.) NO __threadfence: R12's per-block buffer_wbl2
    // was the 61->113us regression.
    if (t == 0) {
        asm volatile("s_waitcnt vmcnt(0) lgkmcnt(0)" ::: "memory");
        lastf = (__hip_atomic_fetch_add(done, 1u, __ATOMIC_RELAXED,
                                        __HIP_MEMORY_SCOPE_AGENT) == 2047u) ? 1 : 0;
    }
    __syncthreads();
    if (lastf) {
        double term = 0.0; int act = 0;
#pragma unroll
        for (int j = 0; j < 2; ++j) {
            const int k = t + (j << 8);
            const unsigned cnt =
                __hip_atomic_load(&hist[k], __ATOMIC_RELAXED, __HIP_MEMORY_SCOPE_AGENT);
            const double pr = (double)cnt * (1.0 / 65536.0);
            term += pr * log(pr + 1e-10);
            act  += (weight[k] >= 0.01f) ? 1 : 0;
        }
#pragma unroll
        for (int off = 32; off > 0; off >>= 1) {
            term += __shfl_down(term, off, 64);
            act  += __shfl_down(act,  off, 64);
        }
        if (lane == 0) { ls_red[wv] = term; c1i[wv] = act; }
        __syncthreads();
        if (t == 0) {
            const double s = (ls_red[0] + ls_red[1]) + (ls_red[2] + ls_red[3]);
            const int    a = c1i[0] + c1i[1] + c1i[2] + c1i[3];
            double ss = 0.0;
#pragma unroll
            for (int p = 0; p < 32; ++p)
                ss += __hip_atomic_load(&ssep[p], __ATOMIC_RELAXED, __HIP_MEMORY_SCOPE_AGENT);
            scal[0] = (float)(ss * (1.0 / 4194304.0));  // commitment_loss
            scal[1] = (float)exp(-s);                   // perplexity
            scal[2] = (float)a;                         // active_codes
        }
    }
}

extern "C" void kernel_launch(void* const* d_in, const int* in_sizes, int n_in,
                              void* d_out, int out_size, void* d_ws, size_t ws_size,
                              hipStream_t stream) {
    const float* x      = (const float*)d_in[0];  // [16,64,64,64] fp32
    const float* emb    = (const float*)d_in[1];  // [512,64] fp32
    const float* weight = (const float*)d_in[2];  // [512] fp32

    float* out = (float*)d_out;
    float*          enorm = (float*)d_ws;
    unsigned short* pfrag = (unsigned short*)((char*)d_ws + 4096);
    double*         ssep  = (double*)((char*)d_ws + 135168);
    unsigned*       hist  = (unsigned*)((char*)d_ws + 135424);
    unsigned*       done  = (unsigned*)((char*)d_ws + 137472);

    float* scal    = out + OUT_ELEMS;      // commitment, perplexity, active
    float* idx_out = out + OUT_ELEMS + 3;  // indices as float [65536]

    vq_prep<<<128, 256, 0, stream>>>(emb, pfrag, enorm, hist, done, ssep);
    vq_main<<<2048, 256, 0, stream>>>(x, emb, pfrag, enorm, weight,
                                      out, idx_out, scal, hist, done, ssep);
}

// Round 3
// 108.609 us; speedup vs baseline: 1.5930x; 1.2873x over previous
//
#include <hip/hip_runtime.h>

// Problem constants
#define HW 4096           // H*W
#define CHW 262144        // C*H*W
#define OUT_ELEMS 4194304 // B*C*H*W
#define FLT_BIG 3.4e38f

typedef __attribute__((ext_vector_type(8))) short  short8;   // MFMA A/B frag (4 VGPR)
typedef __attribute__((ext_vector_type(4))) float  floatx4;  // MFMA C/D frag
typedef __attribute__((ext_vector_type(4))) int    intx4;

// ws layout (no zero-init needed -- every byte read is written first):
//   [0,2048)        enorm f32[512]   -- holds -0.5*||e||^2 (prescaled)
//   [4096,135168)   planes_frag u16 (128 KB, fragment-major split-bf16 codebook)
//   [135168,151552) ws_sse double[2048]  (per-block SSE, plain stores)
//   [151552,184320) part u32[16][512]    (per-hist-block partial histograms)

__device__ __forceinline__ unsigned bf16_rne(float f) {
    unsigned u = __float_as_uint(f);
    return (u + 0x7FFFu + ((u >> 16) & 1u)) >> 16;  // RNE bf16 bits
}

__device__ __forceinline__ void split8(const float* f, intx4* hi, intx4* lo) {
    unsigned h[4], l[4];
#pragma unroll
    for (int j = 0; j < 4; ++j) {
        const unsigned h0 = bf16_rne(f[2 * j]);
        const unsigned h1 = bf16_rne(f[2 * j + 1]);
        const float hf0 = __uint_as_float(h0 << 16);
        const float hf1 = __uint_as_float(h1 << 16);
        const unsigned l0 = bf16_rne(f[2 * j] - hf0);
        const unsigned l1 = bf16_rne(f[2 * j + 1] - hf1);
        h[j] = h0 | (h1 << 16);
        l[j] = l0 | (l1 << 16);
    }
    *hi = intx4{(int)h[0], (int)h[1], (int)h[2], (int)h[3]};
    *lo = intx4{(int)l[0], (int)l[1], (int)l[2], (int)l[3]};
}

// prep: 128 blocks x 256 threads; 4 codes/block (1 wave per code), single
// iteration. enorm stored PRESCALED as -0.5*||e||^2 (R12 trick kept).
__global__ void vq_prep(const float* __restrict__ emb,
                        unsigned short* __restrict__ pfrag,
                        float* __restrict__ enorm) {
    const int t = threadIdx.x;
    const int lane = t & 63;
    const int code = (blockIdx.x << 2) + (t >> 6);
    const int c = lane;
    const float v = emb[(code << 6) + c];            // 256B coalesced per wave
    const unsigned hb = bf16_rne(v);
    const float hf    = __uint_as_float(hb << 16);
    const unsigned lb = bf16_rne(v - hf);
    const int nc = code >> 6, grp = (code & 63) >> 4, n = code & 15;
    const int q = (c & 31) >> 3, o = c & 7;
    const int jh = c >> 5;        // eh element e=c
    const int jl = 2 + (c >> 5);  // el element e=64+c
    pfrag[((((size_t)(nc*4 + jh)*4 + grp)*4 + q)*16 + n)*8 + o] = (unsigned short)hb;
    pfrag[((((size_t)(nc*4 + jl)*4 + grp)*4 + q)*16 + n)*8 + o] = (unsigned short)lb;
    float s = v * v;
#pragma unroll
    for (int off = 32; off > 0; off >>= 1) s += __shfl_xor(s, off, 64);
    if (lane == 0) enorm[code] = -0.5f * s;
}

// Main: 2048 blocks x 256 threads; 32 rows/block.
// R14 = R13's compute core + R11's atomic-free aux structure.
// Post-mortem R12/R13: the fused hist/ssep/done tail cost ~27us of in-kernel
// stall (device-scope RMWs at the coherent point, __syncthreads parking all
// waves behind them; WRITE_SIZE +1.8MB was the tell), while fusing dispatches
// saved only ~9us of a ~55us fixed chain overhead. So: NO device atomics in
// this kernel. Plain ws_sse[blk] store; hist/scal in trailing tiny kernels
// (kernel-boundary ordering provides coherence, R9-proven).
// Kept from R12/R13 (verified: VALU work halved vs R11):
//  * swapped MFMA operands (codes=A, x=B): each lane owns one x-row with 16
//    codes in (quad,reg); acc IS the score, per-distance fmaf gone.
//  * enorm off the MFMA critical path: zero-init accs, -0.5*||e||^2 float4s
//    load at iteration top, added at selection time (monotone, same
//    tie-break; exact fp64 verify unchanged).
//  * cross-lane tournament: 2 shfl rounds x 1 track (was 4 x 4).
__global__ __launch_bounds__(256)
void vq_main(const float* __restrict__ x_in, const float* __restrict__ emb,
             const unsigned short* __restrict__ pfrag,
             const float* __restrict__ enorm,
             float* __restrict__ out, float* __restrict__ idx_out,
             double* __restrict__ ws_sse) {
    __shared__ float  b1s[2][32], b2s[2][32];
    __shared__ int    i1s[2][32], i2s[2][32];
    __shared__ int    c1i[32], c2i[32], qidx[32];
    __shared__ double parts[8][32];
    __shared__ double ls_red[4];

    const int t     = threadIdx.x;
    const int lane  = t & 63;
    const int wv    = t >> 6;
    const int col   = lane & 15;
    const int quad  = lane >> 4;
    const int blk   = blockIdx.x;
    const int mrow0 = (wv >> 1) << 4;   // wave row base (0/16)
    const int khalf = wv & 1;           // code-half of each 64-chunk
    const int ncol0 = khalf << 5;
    const int half = blk & 1;           // which 32-w half of the stripe
    const int bh = blk >> 1;
    const int b = bh >> 6, h = bh & 63;
    const float* xb = x_in + (size_t)b * CHW + h * 64 + (half << 5);

    // ---- X-frags: one 16-row M-tile, direct from BCHW global (coalesced),
    // split-bf16, register-resident. Used as the MFMA *B* operand. ----
    short8 Xh[2], Xl[2];
#pragma unroll
    for (int u = 0; u < 2; ++u) {
        float f[8];
#pragma unroll
        for (int j = 0; j < 8; ++j) {
            const int c = (u << 5) + (quad << 3) + j;
            f[j] = xb[(size_t)c * HW + mrow0 + col];
        }
        intx4 hi, lo;
        split8(f, &hi, &lo);
        Xh[u] = __builtin_bit_cast(short8, hi);
        Xl[u] = __builtin_bit_cast(short8, lo);
    }

    // Two per-lane top-2 tracks (nt=0 / nt=1) for ILP; merged before butterfly.
    float B1a = -FLT_BIG, B2a = -FLT_BIG, B1b = -FLT_BIG, B2b = -FLT_BIG;
    int   I1a = 0x3FFFFFFF, I2a = 0x3FFFFFFF, I1b = 0x3FFFFFFF, I2b = 0x3FFFFFFF;

    const char*  pf  = (const char*)pfrag + (size_t)lane * 16 + ((size_t)khalf << 11);
    const float* enp = enorm + ncol0 + (quad << 2);

#pragma unroll 2
    for (int nc = 0; nc < 8; ++nc) {
        const char* base = pf + ((size_t)nc << 14);
        const int K0 = nc << 6;
        // -0.5*||e||^2 for this lane's 8 codes; loads issue here, first use is
        // at selection below -> fully hidden under the MFMA chain.
        const floatx4 e0v = *(const floatx4*)(enp + K0);
        const floatx4 e1v = *(const floatx4*)(enp + K0 + 16);
        floatx4 a0{0.f,0.f,0.f,0.f}, a1{0.f,0.f,0.f,0.f};
#define BLD(j, g) (*(const short8*)(base + ((j) << 12) + ((g) << 10)))
        {   // j=0: eh c[0,32) x {xh,xl}
            const short8 e0 = BLD(0, 0), e1 = BLD(0, 1);
            a0 = __builtin_amdgcn_mfma_f32_16x16x32_bf16(e0, Xh[0], a0, 0, 0, 0);
            a1 = __builtin_amdgcn_mfma_f32_16x16x32_bf16(e1, Xh[0], a1, 0, 0, 0);
            a0 = __builtin_amdgcn_mfma_f32_16x16x32_bf16(e0, Xl[0], a0, 0, 0, 0);
            a1 = __builtin_amdgcn_mfma_f32_16x16x32_bf16(e1, Xl[0], a1, 0, 0, 0);
        }
        {   // j=1: eh c[32,64) x {xh,xl}
            const short8 e0 = BLD(1, 0), e1 = BLD(1, 1);
            a0 = __builtin_amdgcn_mfma_f32_16x16x32_bf16(e0, Xh[1], a0, 0, 0, 0);
            a1 = __builtin_amdgcn_mfma_f32_16x16x32_bf16(e1, Xh[1], a1, 0, 0, 0);
            a0 = __builtin_amdgcn_mfma_f32_16x16x32_bf16(e0, Xl[1], a0, 0, 0, 0);
            a1 = __builtin_amdgcn_mfma_f32_16x16x32_bf16(e1, Xl[1], a1, 0, 0, 0);
        }
        {   // j=2: el c[0,32) x xh
            const short8 e0 = BLD(2, 0), e1 = BLD(2, 1);
            a0 = __builtin_amdgcn_mfma_f32_16x16x32_bf16(e0, Xh[0], a0, 0, 0, 0);
            a1 = __builtin_amdgcn_mfma_f32_16x16x32_bf16(e1, Xh[0], a1, 0, 0, 0);
        }
        {   // j=3: el c[32,64) x xh
            const short8 e0 = BLD(3, 0), e1 = BLD(3, 1);
            a0 = __builtin_amdgcn_mfma_f32_16x16x32_bf16(e0, Xh[1], a0, 0, 0, 0);
            a1 = __builtin_amdgcn_mfma_f32_16x16x32_bf16(e1, Xh[1], a1, 0, 0, 0);
        }
#undef BLD

        const int cb = K0 + ncol0 + (quad << 2);
#pragma unroll
        for (int reg = 0; reg < 4; ++reg) {
            const float da = a0[reg] + e0v[reg];   // = dot - ||e||^2/2 = -d/2
            if (da > B1a)      { B2a = B1a; I2a = I1a; B1a = da; I1a = cb + reg; }
            else if (da > B2a) { B2a = da; I2a = cb + reg; }
            const float db = a1[reg] + e1v[reg];
            if (db > B1b)      { B2b = B1b; I2b = I1b; B1b = db; I1b = cb + 16 + reg; }
            else if (db > B2b) { B2b = db; I2b = cb + 16 + reg; }
        }
    }

    // ---- merge the two tracks (disjoint code sets, index tie-break) ----
    float B1, B2; int I1, I2;
    if (B1b > B1a || (B1b == B1a && I1b < I1a)) {
        B1 = B1b; I1 = I1b;
        if (B1a > B2b || (B1a == B2b && I1a < I2b)) { B2 = B1a; I2 = I1a; }
        else                                        { B2 = B2b; I2 = I2b; }
    } else {
        B1 = B1a; I1 = I1a;
        if (B1b > B2a || (B1b == B2a && I1b < I2a)) { B2 = B1b; I2 = I1b; }
        else                                        { B2 = B2a; I2 = I2a; }
    }

    // ---- cross-lane top-2 butterfly over QUADS only (off 16,32) ----
#pragma unroll
    for (int off = 16; off <= 32; off <<= 1) {
        const float ob1 = __shfl_xor(B1, off, 64);
        const int   oi1 = __shfl_xor(I1, off, 64);
        const float ob2 = __shfl_xor(B2, off, 64);
        const int   oi2 = __shfl_xor(I2, off, 64);
        if (ob1 > B1 || (ob1 == B1 && oi1 < I1)) {
            float nb2; int ni2;
            if (B1 > ob2 || (B1 == ob2 && I1 < oi2)) { nb2 = B1; ni2 = I1; }
            else                                     { nb2 = ob2; ni2 = oi2; }
            B1 = ob1; I1 = oi1; B2 = nb2; I2 = ni2;
        } else if (ob1 > B2 || (ob1 == B2 && oi1 < I2)) {
            B2 = ob1; I2 = oi1;
        }
    }
    if (lane < 16) {
        const int row = mrow0 + lane;
        b1s[khalf][row] = B1; b2s[khalf][row] = B2;
        i1s[khalf][row] = I1; i2s[khalf][row] = I2;
    }
    __syncthreads();

    // ---- merge halves -> approx top-2 candidates per row (max-flipped) ----
    if (t < 32) {
        const int r = t;
        float b1 = b1s[0][r], b2 = b2s[0][r];
        int   i1 = i1s[0][r], i2 = i2s[0][r];
        const float c1 = b1s[1][r]; const int j1 = i1s[1][r];
        const float c2 = b2s[1][r]; const int j2 = i2s[1][r];
        if (c1 > b1 || (c1 == b1 && j1 < i1))      { b2 = b1; i2 = i1; b1 = c1; i1 = j1; }
        else if (c1 > b2 || (c1 == b2 && j1 < i2)) { b2 = c1; i2 = j1; }
        if (c2 > b2 || (c2 == b2 && j2 < i2))      { b2 = c2; i2 = j2; }
        c1i[r] = i1; c2i[r] = i2;
    }
    __syncthreads();

    // ---- unconditional 8-way-parallel exact fp64 verify of both candidates:
    // thread group k = t>>5 -> candidate (k&1), c-quarter (k>>1), 16 c each ----
    {
        const int r  = t & 31;
        const int k  = t >> 5;
        const int cq = k >> 1;
        const int code = (k & 1) ? c2i[r] : c1i[r];
        const float* ep = emb + ((size_t)code << 6) + (cq << 4);
        const float* xq = xb + r;   // lanes r consecutive -> coalesced
        double d0 = 0.0, d1 = 0.0;
#pragma unroll
        for (int cc = 0; cc < 16; cc += 2) {
            const int c = (cq << 4) + cc;
            const double f0 = (double)xq[(size_t)c * HW]       - (double)ep[cc];
            const double f1 = (double)xq[(size_t)(c + 1) * HW] - (double)ep[cc + 1];
            d0 = fma(f0, f0, d0);
            d1 = fma(f1, f1, d1);
        }
        parts[k][r] = d0 + d1;
    }
    __syncthreads();
    if (t < 32) {
        const double d1 = parts[0][t] + parts[2][t] + parts[4][t] + parts[6][t];
        const double d2 = parts[1][t] + parts[3][t] + parts[5][t] + parts[7][t];
        int i1 = c1i[t];
        const int i2 = c2i[t];
        if (d2 < d1 || (d2 == d1 && i2 < i1)) i1 = i2; // lowest-index tie-break
        qidx[t] = i1;
        idx_out[(blk << 5) + t] = (float)i1;
    }
    __syncthreads();

    // ---- epilogue: quantized out (coalesced along w) + per-block SSE ----
    {
        const int r  = t & 31;
        const int c0 = (t >> 5) << 3;    // 8 channels per thread-group
        const float* xp = xb + r;
        float*       op = out + (size_t)b * CHW + h * 64 + (half << 5) + r;
        const float* eq = emb + ((size_t)qidx[r] << 6);
        float sse_local = 0.f;
#pragma unroll
        for (int cc = 0; cc < 8; ++cc) {
            const int c = c0 + cc;
            const float qc = eq[c];
            const float dx = qc - xp[(size_t)c * HW];
            sse_local = fmaf(dx, dx, sse_local);
            op[(size_t)c * HW] = qc;
        }
#pragma unroll
        for (int off = 32; off > 0; off >>= 1)
            sse_local += __shfl_down(sse_local, off, 64);
        if (lane == 0) ls_red[wv] = (double)sse_local;
        __syncthreads();
        if (t == 0)
            ws_sse[blk] = (ls_red[0] + ls_red[1]) + (ls_red[2] + ls_red[3]);  // plain store
    }
}

// hist: 16 blocks x 256 threads; LDS histogram of 4096 indices each, plain
// partial-store. Kernel-boundary ordering provides coherence (R9-proven).
__global__ void vq_hist(const float* __restrict__ idx_out,
                        unsigned* __restrict__ part) {
    __shared__ unsigned hs[512];
    const int t = threadIdx.x;
    hs[t] = 0u; hs[t + 256] = 0u;
    __syncthreads();
    const float4* ip = (const float4*)(idx_out + (blockIdx.x << 12));
#pragma unroll
    for (int i = 0; i < 4; ++i) {
        const float4 v = ip[(i << 8) + t];    // coalesced
        atomicAdd(&hs[(int)v.x], 1u);         // LDS atomics
        atomicAdd(&hs[(int)v.y], 1u);
        atomicAdd(&hs[(int)v.z], 1u);
        atomicAdd(&hs[(int)v.w], 1u);
    }
    __syncthreads();
    unsigned* pp = part + (blockIdx.x << 9);
    pp[t] = hs[t]; pp[t + 256] = hs[t + 256];  // coalesced plain stores
}

// scal: 1 block x 512 threads. Partial hists -> perplexity; ws_sse ->
// commitment; weight -> active codes.
__global__ void vq_scal(const unsigned* __restrict__ part,
                        const double* __restrict__ ws_sse,
                        const float* __restrict__ weight,
                        float* __restrict__ scal) {
    __shared__ double redt[8], reds[8];
    __shared__ int    redi[8];
    const int k = threadIdx.x;       // 0..511 = code
    const int lane = k & 63, wv = k >> 6;
    unsigned cnt = 0;
#pragma unroll
    for (int p = 0; p < 16; ++p) cnt += part[(p << 9) + k];   // coalesced per p
    const double pr = (double)cnt / 65536.0;
    double term = pr * log(pr + 1e-10);
    double ssep = 0.0;
#pragma unroll
    for (int j = 0; j < 4; ++j) ssep += ws_sse[k + (j << 9)];
    int act = (weight[k] >= 0.01f) ? 1 : 0;
#pragma unroll
    for (int off = 32; off > 0; off >>= 1) {
        term += __shfl_down(term, off, 64);
        ssep += __shfl_down(ssep, off, 64);
        act  += __shfl_down(act,  off, 64);
    }
    if (lane == 0) { redt[wv] = term; reds[wv] = ssep; redi[wv] = act; }
    __syncthreads();
    if (k == 0) {
        double s = 0.0, ss = 0.0; int a = 0;
#pragma unroll
        for (int i = 0; i < 8; ++i) { s += redt[i]; ss += reds[i]; a += redi[i]; }
        scal[0] = (float)(ss / 4194304.0);  // commitment_loss
        scal[1] = (float)exp(-s);           // perplexity
        scal[2] = (float)a;                 // active_codes
    }
}

extern "C" void kernel_launch(void* const* d_in, const int* in_sizes, int n_in,
                              void* d_out, int out_size, void* d_ws, size_t ws_size,
                              hipStream_t stream) {
    const float* x      = (const float*)d_in[0];  // [16,64,64,64] fp32
    const float* emb    = (const float*)d_in[1];  // [512,64] fp32
    const float* weight = (const float*)d_in[2];  // [512] fp32

    float* out = (float*)d_out;
    float*          enorm  = (float*)d_ws;
    unsigned short* pfrag  = (unsigned short*)((char*)d_ws + 4096);
    double*         ws_sse = (double*)((char*)d_ws + 135168);
    unsigned*       part   = (unsigned*)((char*)d_ws + 151552);

    float* scal    = out + OUT_ELEMS;      // commitment, perplexity, active
    float* idx_out = out + OUT_ELEMS + 3;  // indices as float [65536]

    vq_prep<<<128, 256, 0, stream>>>(emb, pfrag, enorm);
    vq_main<<<2048, 256, 0, stream>>>(x, emb, pfrag, enorm, out, idx_out, ws_sse);
    vq_hist<<<16, 256, 0, stream>>>(idx_out, part);
    vq_scal<<<1, 512, 0, stream>>>(part, ws_sse, weight, scal);
}